// Round 16
// baseline (35.860 us; speedup 1.0000x reference)
//
#include <hip/hip_runtime.h>
#include <hip/hip_bf16.h>

#define TT 2048
#define HH 1024
#define NTAGS 74
#define NPAD 80
#define CHK 64            // K elements per chunk
#define NCH (HH / CHK)    // 16 chunks
#define MROWS 64          // rows per block
#define THREADS 256
#define NXCD 8

typedef __bf16 bf16x8 __attribute__((ext_vector_type(8)));
typedef float f32x4 __attribute__((ext_vector_type(4)));

// Transpose + convert W_out [1024][74] f32 -> Wt [80][1024] bf16 (pad cols 74..79 = 0)
__global__ __launch_bounds__(256) void prep_w_kernel(const float* __restrict__ W,
                                                     __bf16* __restrict__ Wt) {
    __shared__ float tile[64][80];
    const int k0 = blockIdx.x * 64;
    const int tid = threadIdx.x;
    for (int i = tid; i < 64 * NTAGS; i += 256) {
        int k = i / NTAGS, n = i - k * NTAGS;
        tile[k][n] = W[(k0 + k) * NTAGS + n];
    }
    __syncthreads();
    for (int i = tid; i < NPAD * 64; i += 256) {
        int n = i >> 6, kk = i & 63;
        float v = (n < NTAGS) ? tile[kk][n] : 0.0f;
        Wt[n * HH + k0 + kk] = (__bf16)v;
    }
}

// R16 = R12/R15 skeleton + WORD DEDUP. word_idx is non-decreasing (step <=1),
// so a 64-row block references only nw<=64 CONSECUTIVE word rows [w0, w0+nw).
// Stage those unique rows once per chunk (contiguous, coalesced) instead of
// one word-row copy per position: word VMEM 100->~40 MB (avg nw~26).
// Blend moves to fragment-build: lane reads char frag + word frag
// (u_my = widx[myrow]-w0) from LDS, blends with its own row's rate.
// char/word staged as bf16 (cvt at commit): LDS = char 2x8K @0,
// word 2x8K @16384, W 2x10K @32768 = 52 KB, double-buffered.
// Pipeline unchanged: commit regs(ch+1) -> issue loads(ch+2) -> MFMA(ch) -> bar.
__global__ __launch_bounds__(256, 2) void slu_main(const float* __restrict__ out_char,
                                                   const float* __restrict__ out_word,
                                                   const int* __restrict__ word_idx,
                                                   const int* __restrict__ is_head,
                                                   const int* __restrict__ valid_mask,
                                                   const __bf16* __restrict__ Wt,
                                                   const float* __restrict__ b_out,
                                                   float* __restrict__ out) {
    __shared__ __align__(16) char smem[53248];
    const int tid = threadIdx.x;
    const int wv = tid >> 6;
    const int lane = tid & 63;
    const int l15 = lane & 15;
    const int kgrp = lane >> 4;

    // ---- XCD-aware bijective swizzle (512 blocks = 8 XCDs x 64 chunks) ----
    const int bid = blockIdx.x;
    const int rb = (bid & (NXCD - 1)) * (512 / NXCD) + (bid >> 3);
    const int rowbase = rb * MROWS;
    const int batch = rowbase >> 11;  // T = 2048
    const size_t batbase = (size_t)batch * TT;

    // ---- char staging descriptor: row rloc=tid>>2, 16-f32 piece q=tid&3 ----
    const int rloc = tid >> 2;
    const int q = tid & 3;
    const int r = rowbase + rloc;
    const int val = valid_mask[r];

    // ---- early-exit: fully-invalid block writes bias rows and returns ----
    if (!__syncthreads_or(val)) {
        for (int i = tid; i < MROWS * NTAGS; i += THREADS) {
            const int rr = i / NTAGS, cc = i - rr * NTAGS;
            out[(size_t)(rowbase + rr) * NTAGS + cc] = b_out[cc];
        }
        return;
    }

    // ---- unique word range for this block: [w0, w0+nw), nw <= 64 ----
    int wmaxv = word_idx[rowbase + lane];
#pragma unroll
    for (int m = 1; m < 64; m <<= 1) {
        const int o = __shfl_xor(wmaxv, m);
        wmaxv = (o > wmaxv) ? o : wmaxv;
    }
    const int w0 = word_idx[rowbase];   // row 0 of block valid (else early-exit)
    const int nw = wmaxv - w0 + 1;      // 1..64

    // ---- char source + LDS write offsets (bf16 layout: row stride 128 B) ----
    const float* cptr = out_char + (size_t)r * HH + q * 16;
    const int csw = (rloc & 7) << 4;
    const int cwr0 = (rloc * 128 + q * 32) ^ csw;
    const int cwr1 = (rloc * 128 + q * 32 + 16) ^ csw;

    // ---- word staging: unique row uloc=rloc (predicated rloc<nw), same offsets ----
    const bool wstage = (rloc < nw);
    const float* uptr = out_word + (batbase + w0 + rloc) * HH + q * 16;

    // ---- W staging (R5 map): 640 16B-units/chunk ----
    const int wn0 = tid >> 3, wsb = tid & 7;
    const __bf16* wgp0 = Wt + (size_t)wn0 * HH + wsb * 8;
    const __bf16* wgp1 = wgp0 + 32 * HH;
    const __bf16* wgp2 = wgp0 + 64 * HH;
    const int wsw = (wn0 & 7) << 4;
    const int wwr0 = (wn0 * 128 + wsb * 16) ^ wsw;
    const int wwr1 = ((wn0 + 32) * 128 + wsb * 16) ^ wsw;
    const int wwr2 = ((wn0 + 64) * 128 + wsb * 16) ^ wsw;
    const bool w3 = (tid < 128);

    // ---- my MFMA row's blend params ----
    const int myrow = rowbase + wv * 16 + l15;
    const int myval = valid_mask[myrow];
    const float rt = is_head[myrow] ? 0.88f : 0.70f;
    const float rate = myval ? rt : 0.0f;
    const float crate = myval ? (1.0f - rt) : 0.0f;
    int u_my = word_idx[myrow] - w0;
    if (u_my < 0) u_my = 0;  // invalid rows (widx=0); rate=0 kills the value

    // ---- fragment read offsets ----
    const int mysw = (l15 & 7) << 4;
    const int usw2 = (u_my & 7) << 4;
    int cfo[2], ufo[2], woff[2][5];
#pragma unroll
    for (int s = 0; s < 2; ++s) {
        cfo[s] = ((wv * 16 + l15) * 128 + s * 64 + kgrp * 16) ^ mysw;
        ufo[s] = (u_my * 128 + s * 64 + kgrp * 16) ^ usw2;
#pragma unroll
        for (int nt = 0; nt < 5; ++nt)
            woff[s][nt] = ((nt * 16 + l15) * 128 + s * 64 + kgrp * 16) ^ mysw;
    }

    f32x4 acc[5];
#pragma unroll
    for (int nt = 0; nt < 5; ++nt) acc[nt] = (f32x4){0.f, 0.f, 0.f, 0.f};

    float4 cc[4], uc[4];   // held loads (chunk ch+2)
    bf16x8 wreg0, wreg1, wreg2;

#define PACK2(dst0, dst1, src, pred)                                     \
    {                                                                    \
        bf16x8 f0_, f1_;                                                 \
        if (pred) {                                                      \
            _Pragma("unroll") for (int i_ = 0; i_ < 2; ++i_) {           \
                f0_[i_ * 4 + 0] = (__bf16)src[i_].x;                     \
                f0_[i_ * 4 + 1] = (__bf16)src[i_].y;                     \
                f0_[i_ * 4 + 2] = (__bf16)src[i_].z;                     \
                f0_[i_ * 4 + 3] = (__bf16)src[i_].w;                     \
                f1_[i_ * 4 + 0] = (__bf16)src[i_ + 2].x;                 \
                f1_[i_ * 4 + 1] = (__bf16)src[i_ + 2].y;                 \
                f1_[i_ * 4 + 2] = (__bf16)src[i_ + 2].z;                 \
                f1_[i_ * 4 + 3] = (__bf16)src[i_ + 2].w;                 \
            }                                                            \
        } else {                                                         \
            f0_ = (bf16x8)0; f1_ = (bf16x8)0;                            \
        }                                                                \
        *(bf16x8*)(dst0) = f0_;                                          \
        *(bf16x8*)(dst1) = f1_;                                          \
    }

    // ---- prologue: stage chunk 0 directly; prefetch chunk 1 into regs ----
    {
        float4 c0[4], u0[4];
        if (val) {
#pragma unroll
            for (int i = 0; i < 4; ++i) c0[i] = *(const float4*)(cptr + i * 4);
        }
        if (wstage) {
#pragma unroll
            for (int i = 0; i < 4; ++i) u0[i] = *(const float4*)(uptr + i * 4);
        }
        bf16x8 wr0 = *(const bf16x8*)(wgp0);
        bf16x8 wr1 = *(const bf16x8*)(wgp1);
        bf16x8 wr2 = w3 ? *(const bf16x8*)(wgp2) : (bf16x8)0;
        PACK2(smem + cwr0, smem + cwr1, c0, val);
        if (wstage) PACK2(smem + 16384 + cwr0, smem + 16384 + cwr1, u0, true);
        *(bf16x8*)(smem + 32768 + wwr0) = wr0;
        *(bf16x8*)(smem + 32768 + wwr1) = wr1;
        if (w3) *(bf16x8*)(smem + 32768 + wwr2) = wr2;
        if (val) {
#pragma unroll
            for (int i = 0; i < 4; ++i) cc[i] = *(const float4*)(cptr + CHK + i * 4);
        }
        if (wstage) {
#pragma unroll
            for (int i = 0; i < 4; ++i) uc[i] = *(const float4*)(uptr + CHK + i * 4);
        }
        wreg0 = *(const bf16x8*)(wgp0 + CHK);
        wreg1 = *(const bf16x8*)(wgp1 + CHK);
        wreg2 = w3 ? *(const bf16x8*)(wgp2 + CHK) : (bf16x8)0;
    }
    __syncthreads();

    // ---- main loop ----
    for (int ch = 0; ch < NCH; ++ch) {
        // 1) commit prefetched chunk ch+1 to the other buffer
        if (ch + 1 < NCH) {
            char* Cn = smem + ((ch + 1) & 1) * 8192;
            char* Un = smem + 16384 + ((ch + 1) & 1) * 8192;
            char* Wn = smem + 32768 + ((ch + 1) & 1) * 10240;
            PACK2(Cn + cwr0, Cn + cwr1, cc, val);
            if (wstage) PACK2(Un + cwr0, Un + cwr1, uc, true);
            *(bf16x8*)(Wn + wwr0) = wreg0;
            *(bf16x8*)(Wn + wwr1) = wreg1;
            if (w3) *(bf16x8*)(Wn + wwr2) = wreg2;
        }
        // 2) issue global loads for chunk ch+2 (held in regs across compute)
        if (ch + 2 < NCH) {
            const int ko = (ch + 2) * CHK;
            if (val) {
#pragma unroll
                for (int i = 0; i < 4; ++i) cc[i] = *(const float4*)(cptr + ko + i * 4);
            }
            if (wstage) {
#pragma unroll
                for (int i = 0; i < 4; ++i) uc[i] = *(const float4*)(uptr + ko + i * 4);
            }
            wreg0 = *(const bf16x8*)(wgp0 + ko);
            wreg1 = *(const bf16x8*)(wgp1 + ko);
            wreg2 = w3 ? *(const bf16x8*)(wgp2 + ko) : (bf16x8)0;
        }
        // 3) compute chunk ch: per s, read char+word frags, blend, 5 MFMA
        const char* Cb = smem + (ch & 1) * 8192;
        const char* Ub = smem + 16384 + (ch & 1) * 8192;
        const char* Wb = smem + 32768 + (ch & 1) * 10240;
#pragma unroll
        for (int s = 0; s < 2; ++s) {
            bf16x8 cf = *(const bf16x8*)(Cb + cfo[s]);
            bf16x8 uf = *(const bf16x8*)(Ub + ufo[s]);
            bf16x8 a;
#pragma unroll
            for (int e = 0; e < 8; ++e)
                a[e] = (__bf16)((float)uf[e] * rate + (float)cf[e] * crate);
#pragma unroll
            for (int nt = 0; nt < 5; ++nt) {
                bf16x8 bw = *(const bf16x8*)(Wb + woff[s][nt]);
                acc[nt] = __builtin_amdgcn_mfma_f32_16x16x32_bf16(a, bw, acc[nt], 0, 0, 0);
            }
        }
        __syncthreads();
    }

    // ---- epilogue: C/D col = lane&15, row = (lane>>4)*4 + reg  [verified R2-R15] ----
    const int orow = rowbase + wv * 16 + kgrp * 4;
#pragma unroll
    for (int nt = 0; nt < 5; ++nt) {
        const int col = nt * 16 + l15;
        if (col < NTAGS) {
            const float bias = b_out[col];
#pragma unroll
            for (int i = 0; i < 4; ++i) {
                out[(size_t)(orow + i) * NTAGS + col] = acc[nt][i] + bias;
            }
        }
    }
#undef PACK2
}

extern "C" void kernel_launch(void* const* d_in, const int* in_sizes, int n_in,
                              void* d_out, int out_size, void* d_ws, size_t ws_size,
                              hipStream_t stream) {
    const float* out_char = (const float*)d_in[0];
    const float* out_word = (const float*)d_in[1];
    const int* word_idx = (const int*)d_in[2];
    const int* is_head = (const int*)d_in[3];
    const int* valid_mask = (const int*)d_in[4];
    const float* W_out = (const float*)d_in[5];
    const float* b_out = (const float*)d_in[6];
    float* out = (float*)d_out;
    __bf16* Wt = (__bf16*)d_ws;  // 80*1024*2 = 160 KB

    prep_w_kernel<<<HH / 64, 256, 0, stream>>>(W_out, Wt);

    const int rows = 16 * TT;  // B*T = 32768
    slu_main<<<rows / MROWS, THREADS, 0, stream>>>(out_char, out_word, word_idx, is_head,
                                                   valid_mask, Wt, b_out, out);
}